// Round 2
// baseline (246.695 us; speedup 1.0000x reference)
//
#include <hip/hip_runtime.h>

#define ROW_T   8192
#define THREADS 256
#define ITEMS   32          // elements per thread
#define HALF    4096        // staged half-row
#define EPSV    1e-4f

__device__ __forceinline__ float fast_rcp(float v) { return __builtin_amdgcn_rcpf(v); }
__device__ __forceinline__ float fast_rsq(float v) { return __builtin_amdgcn_rsqf(v); }

__global__ __launch_bounds__(THREADS, 8)
void cumnorm_kernel(const float* __restrict__ x, float* __restrict__ out) {
    // half-row staging, +1 float pad per 32-float chunk: 4224 floats = 16896 B
    __shared__ float lds[HALF + HALF / 32];
    __shared__ float wsum[4];
    __shared__ float wssum[4];

    const int t = threadIdx.x;
    const long long rowbase = (long long)blockIdx.x * ROW_T;
    const float* __restrict__ xr = x + rowbase;
    float* __restrict__ outr = out + rowbase;

    float xv[ITEMS];

    // ---- Stage half 0 (coalesced float4) -> padded LDS ----
    #pragma unroll
    for (int j = 0; j < 4; ++j) {
        const int fi = (j * THREADS + t) * 4;           // 0..4092, fi%4==0
        const float4 v = *reinterpret_cast<const float4*>(xr + fi);
        const int p = fi + (fi >> 5);                   // fi..fi+3 stay in one chunk
        lds[p + 0] = v.x; lds[p + 1] = v.y; lds[p + 2] = v.z; lds[p + 3] = v.w;
    }
    __syncthreads();
    // threads 0..127 (waves 0,1 — wave-uniform branch) read their chunks
    if (t < 128) {
        const int cb = t * 33;
        #pragma unroll
        for (int j = 0; j < ITEMS; ++j) xv[j] = lds[cb + j];
    }
    __syncthreads();

    // ---- Stage half 1 ----
    #pragma unroll
    for (int j = 0; j < 4; ++j) {
        const int fi = (j * THREADS + t) * 4;
        const float4 v = *reinterpret_cast<const float4*>(xr + HALF + fi);
        const int p = fi + (fi >> 5);
        lds[p + 0] = v.x; lds[p + 1] = v.y; lds[p + 2] = v.z; lds[p + 3] = v.w;
    }
    __syncthreads();
    if (t >= 128) {
        const int cb = (t - 128) * 33;
        #pragma unroll
        for (int j = 0; j < ITEMS; ++j) xv[j] = lds[cb + j];
    }

    // ---- Per-thread totals ----
    float s = 0.f, ss = 0.f;
    #pragma unroll
    for (int j = 0; j < ITEMS; ++j) {
        s += xv[j];
        ss = fmaf(xv[j], xv[j], ss);
    }

    // ---- Block-wide exclusive scan of (s, ss) ----
    const int lane = t & 63;
    const int wid  = t >> 6;
    float is = s, iss = ss;
    #pragma unroll
    for (int off = 1; off < 64; off <<= 1) {
        const float us  = __shfl_up(is, off);
        const float uss = __shfl_up(iss, off);
        if (lane >= off) { is += us; iss += uss; }
    }
    if (lane == 63) { wsum[wid] = is; wssum[wid] = iss; }
    __syncthreads();

    float carry_s = 0.f, carry_ss = 0.f;
    #pragma unroll
    for (int w = 0; w < 4; ++w) {
        if (w < wid) { carry_s += wsum[w]; carry_ss += wssum[w]; }
    }
    float S  = carry_s  + (is  - s);    // exclusive prefix sums
    float SS = carry_ss + (iss - ss);

    // ---- Normalize in registers ----
    const int ebase = t * ITEMS;
    #pragma unroll
    for (int j = 0; j < ITEMS; ++j) {
        const float v = xv[j];
        S += v;
        SS = fmaf(v, v, SS);
        const float inv  = fast_rcp((float)(ebase + j + 1));
        const float mean = S * inv;
        const float var  = fmaf(SS, inv, -(mean * mean));
        xv[j] = (v - mean) * fast_rsq(var + EPSV);
    }

    // ---- Direct per-thread contiguous float4 stores (lane fills its own 128B line) ----
    #pragma unroll
    for (int j = 0; j < 8; ++j) {
        float4 v;
        v.x = xv[4 * j + 0]; v.y = xv[4 * j + 1];
        v.z = xv[4 * j + 2]; v.w = xv[4 * j + 3];
        *reinterpret_cast<float4*>(outr + ebase + j * 4) = v;
    }
}

extern "C" void kernel_launch(void* const* d_in, const int* in_sizes, int n_in,
                              void* d_out, int out_size, void* d_ws, size_t ws_size,
                              hipStream_t stream) {
    const float* x = (const float*)d_in[0];
    float* out = (float*)d_out;
    const int rows = out_size / ROW_T;   // 4096
    cumnorm_kernel<<<rows, THREADS, 0, stream>>>(x, out);
}

// Round 3
// 231.633 us; speedup vs baseline: 1.0650x; 1.0650x over previous
//
#include <hip/hip_runtime.h>

#define ROW_T   8192
#define TILE    2048          // elements per wave-tile (64 lanes x 32)
#define NT      4             // tiles per row
#define WAVES   4
#define THREADS (WAVES * 64)
#define WSLOT   (TILE + TILE / 32)   // 2112 floats, pad-1 per 32-chunk
#define EPSV    1e-4f

__global__ __launch_bounds__(THREADS, 4)
void cumnorm_kernel(const float* __restrict__ x, float* __restrict__ out) {
    __shared__ float lds[WAVES * WSLOT];   // 33792 B -> 4 blocks/CU

    const int t    = threadIdx.x;
    const int lane = t & 63;
    const int wid  = t >> 6;
    float* __restrict__ sl = lds + wid * WSLOT;   // private wave slice: no barriers

    const int row = blockIdx.x * WAVES + wid;
    const float* __restrict__ xr   = x   + (long long)row * ROW_T;
    float* __restrict__       outr = out + (long long)row * ROW_T;

    float carry_s = 0.f, carry_ss = 0.f;

    // prefetch tile 0 (coalesced: 8 x dwordx4, 1 KiB/instr per wave)
    float4 pf[8];
    #pragma unroll
    for (int j = 0; j < 8; ++j)
        pf[j] = *reinterpret_cast<const float4*>(xr + j * 256 + lane * 4);

    #pragma unroll
    for (int tt = 0; tt < NT; ++tt) {
        // ---- stage prefetched tile into padded LDS (2-way bank alias = free) ----
        #pragma unroll
        for (int j = 0; j < 8; ++j) {
            const int e = j * 256 + lane * 4;
            const int p = e + (e >> 5);
            sl[p + 0] = pf[j].x; sl[p + 1] = pf[j].y;
            sl[p + 2] = pf[j].z; sl[p + 3] = pf[j].w;
        }

        // ---- issue next tile's global loads now; they hide under compute ----
        if (tt + 1 < NT) {
            #pragma unroll
            for (int j = 0; j < 8; ++j)
                pf[j] = *reinterpret_cast<const float4*>(
                    xr + (tt + 1) * TILE + j * 256 + lane * 4);
        }

        // ---- lane-contiguous chunk from LDS + totals ----
        float xv[32];
        const int cb = lane * 33;
        float s = 0.f, ss = 0.f;
        #pragma unroll
        for (int j = 0; j < 32; ++j) {
            const float v = sl[cb + j];
            xv[j] = v;
            s += v;
            ss = fmaf(v, v, ss);
        }

        // ---- wave-wide inclusive scan of (s, ss) ----
        float is = s, iss = ss;
        #pragma unroll
        for (int off = 1; off < 64; off <<= 1) {
            const float us  = __shfl_up(is, off);
            const float uss = __shfl_up(iss, off);
            if (lane >= off) { is += us; iss += uss; }
        }
        float S  = carry_s  + (is  - s);    // exclusive prefix incl. prior tiles
        float SS = carry_ss + (iss - ss);
        carry_s  += __shfl(is, 63);         // tile total -> carry for next tile
        carry_ss += __shfl(iss, 63);

        // ---- normalize, write back to same LDS slots ----
        const int ebase = tt * TILE + lane * 32;
        #pragma unroll
        for (int j = 0; j < 32; ++j) {
            const float v = xv[j];
            S += v;
            SS = fmaf(v, v, SS);
            const float inv  = __builtin_amdgcn_rcpf((float)(ebase + j + 1));
            const float mean = S * inv;
            const float var  = fmaf(SS, inv, -(mean * mean));
            sl[cb + j] = (v - mean) * __builtin_amdgcn_rsqf(var + EPSV);
        }

        // ---- coalesced float4 store via LDS readback ----
        #pragma unroll
        for (int j = 0; j < 8; ++j) {
            const int e = j * 256 + lane * 4;
            const int p = e + (e >> 5);
            float4 v;
            v.x = sl[p + 0]; v.y = sl[p + 1];
            v.z = sl[p + 2]; v.w = sl[p + 3];
            *reinterpret_cast<float4*>(outr + tt * TILE + e) = v;
        }
    }
}

extern "C" void kernel_launch(void* const* d_in, const int* in_sizes, int n_in,
                              void* d_out, int out_size, void* d_ws, size_t ws_size,
                              hipStream_t stream) {
    const float* x = (const float*)d_in[0];
    float* out = (float*)d_out;
    const int rows = out_size / ROW_T;            // 4096
    cumnorm_kernel<<<rows / WAVES, THREADS, 0, stream>>>(x, out);
}

// Round 4
// 228.677 us; speedup vs baseline: 1.0788x; 1.0129x over previous
//
#include <hip/hip_runtime.h>

#define ROW_T   8192
#define THREADS 256
#define ITEMS   4
#define STILE   (THREADS * ITEMS)   // 1024 elems per block-tile
#define NST     (ROW_T / STILE)     // 8 tiles per row
#define EPSV    1e-4f

__global__ __launch_bounds__(THREADS, 8)
void cumnorm_kernel(const float* __restrict__ x, float* __restrict__ out) {
    // only wave totals go through LDS; parity-buffered -> 1 barrier per tile
    __shared__ float wbs[2][4];
    __shared__ float wbss[2][4];

    const int t    = threadIdx.x;
    const int lane = t & 63;
    const int wid  = t >> 6;

    const float* __restrict__ xr   = x   + (long long)blockIdx.x * ROW_T;
    float* __restrict__       outr = out + (long long)blockIdx.x * ROW_T;

    float carry_s = 0.f, carry_ss = 0.f;

    // register double-buffer: fully coalesced float4 (lane stride 16B)
    float4 cur = *reinterpret_cast<const float4*>(xr + t * ITEMS);
    float4 nxt;

    #pragma unroll
    for (int k = 0; k < NST; ++k) {
        if (k + 1 < NST)
            nxt = *reinterpret_cast<const float4*>(xr + (k + 1) * STILE + t * ITEMS);

        // ---- local (s, ss) over this thread's 4 consecutive elems ----
        float s  = ((cur.x + cur.y) + (cur.z + cur.w));
        float ss = fmaf(cur.x, cur.x, fmaf(cur.y, cur.y,
                   fmaf(cur.z, cur.z, cur.w * cur.w)));

        // ---- wave-wide inclusive scan of (s, ss) ----
        float is = s, iss = ss;
        #pragma unroll
        for (int off = 1; off < 64; off <<= 1) {
            const float us  = __shfl_up(is, off);
            const float uss = __shfl_up(iss, off);
            if (lane >= off) { is += us; iss += uss; }
        }
        if (lane == 63) { wbs[k & 1][wid] = is; wbss[k & 1][wid] = iss; }
        __syncthreads();

        // ---- cross-wave combine + running row carry ----
        float cs = carry_s, css = carry_ss;
        #pragma unroll
        for (int w = 0; w < 4; ++w) {
            const float a = wbs[k & 1][w], b = wbss[k & 1][w];
            if (w < wid) { cs += a; css += b; }
            carry_s += a; carry_ss += b;       // full tile total for next tile
        }

        float S  = cs  + (is  - s);    // exclusive prefix at this thread's first elem
        float SS = css + (iss - ss);

        // ---- finish serially over own 4 elems, normalize ----
        const int e0 = k * STILE + t * ITEMS;
        float4 o;
        {
            const float v = cur.x; S += v; SS = fmaf(v, v, SS);
            const float inv = __builtin_amdgcn_rcpf((float)(e0 + 1));
            const float mean = S * inv;
            const float var  = fmaf(SS, inv, -(mean * mean));
            o.x = (v - mean) * __builtin_amdgcn_rsqf(var + EPSV);
        }
        {
            const float v = cur.y; S += v; SS = fmaf(v, v, SS);
            const float inv = __builtin_amdgcn_rcpf((float)(e0 + 2));
            const float mean = S * inv;
            const float var  = fmaf(SS, inv, -(mean * mean));
            o.y = (v - mean) * __builtin_amdgcn_rsqf(var + EPSV);
        }
        {
            const float v = cur.z; S += v; SS = fmaf(v, v, SS);
            const float inv = __builtin_amdgcn_rcpf((float)(e0 + 3));
            const float mean = S * inv;
            const float var  = fmaf(SS, inv, -(mean * mean));
            o.z = (v - mean) * __builtin_amdgcn_rsqf(var + EPSV);
        }
        {
            const float v = cur.w; S += v; SS = fmaf(v, v, SS);
            const float inv = __builtin_amdgcn_rcpf((float)(e0 + 4));
            const float mean = S * inv;
            const float var  = fmaf(SS, inv, -(mean * mean));
            o.w = (v - mean) * __builtin_amdgcn_rsqf(var + EPSV);
        }

        *reinterpret_cast<float4*>(outr + e0) = o;   // coalesced store
        cur = nxt;
    }
}

extern "C" void kernel_launch(void* const* d_in, const int* in_sizes, int n_in,
                              void* d_out, int out_size, void* d_ws, size_t ws_size,
                              hipStream_t stream) {
    const float* x = (const float*)d_in[0];
    float* out = (float*)d_out;
    const int rows = out_size / ROW_T;   // 4096
    cumnorm_kernel<<<rows, THREADS, 0, stream>>>(x, out);
}